// Round 2
// baseline (427.662 us; speedup 1.0000x reference)
//
#include <hip/hip_runtime.h>

#define DIM 128
#define MOMENTUM 0.5f

// Grid-stride float4 copy: memory -> out. Same streaming pattern as the
// runtime's fill kernels (which measure 6.5 TB/s on this chip).
__global__ void FeatureBank_copy(const float4* __restrict__ src,
                                 float4* __restrict__ dst,
                                 long long n4) {
    long long i = (long long)blockIdx.x * blockDim.x + threadIdx.x;
    const long long stride = (long long)gridDim.x * blockDim.x;
    for (; i < n4; i += stride)
        dst[i] = src[i];
}

// One wave (64 lanes) per row; lane owns a float2 (128 floats/row).
// Reads the old row from `memory` (input), writes the normalized blend to
// `out`. Must run after the copy (stream order) so the copy's write of the
// same row doesn't clobber it.
__global__ void FeatureBank_update_rows(const float* __restrict__ x,
                                        const int* __restrict__ y,
                                        const float* __restrict__ memory,
                                        float* __restrict__ out,
                                        int batch) {
    const int lane = threadIdx.x & 63;
    const int wave = threadIdx.x >> 6;
    const int row = blockIdx.x * (blockDim.x >> 6) + wave;
    if (row >= batch) return;

    const long long dst = (long long)y[row] * DIM;

    const float2 xv = ((const float2*)(x + (long long)row * DIM))[lane];
    const float2 mv = ((const float2*)(memory + dst))[lane];

    float2 w;
    w.x = MOMENTUM * mv.x + (1.0f - MOMENTUM) * xv.x;
    w.y = MOMENTUM * mv.y + (1.0f - MOMENTUM) * xv.y;

    float ss = w.x * w.x + w.y * w.y;
    #pragma unroll
    for (int off = 32; off > 0; off >>= 1)
        ss += __shfl_xor(ss, off, 64);

    const float inv = rsqrtf(ss);
    float2 o;
    o.x = w.x * inv;
    o.y = w.y * inv;
    ((float2*)(out + dst))[lane] = o;
}

extern "C" void kernel_launch(void* const* d_in, const int* in_sizes, int n_in,
                              void* d_out, int out_size, void* d_ws, size_t ws_size,
                              hipStream_t stream) {
    const float* x      = (const float*)d_in[0];
    const int*   y      = (const int*)d_in[1];
    const float* memory = (const float*)d_in[2];
    float*       out    = (float*)d_out;

    const int batch = in_sizes[1];                  // 4096
    const long long n4 = (long long)out_size / 4;   // 16,000,000 float4s

    // Bulk copy memory -> out with a streaming kernel.
    const int cblock = 256;
    const int cgrid = 4096;                          // 16 blocks/CU, grid-stride
    FeatureBank_copy<<<cgrid, cblock, 0, stream>>>(
        (const float4*)memory, (float4*)out, n4);

    // Overwrite the touched rows.
    const int waves_per_block = 4;                   // 256 threads
    const int block = 64 * waves_per_block;
    const int grid = (batch + waves_per_block - 1) / waves_per_block;
    FeatureBank_update_rows<<<grid, block, 0, stream>>>(x, y, memory, out, batch);
}